// Round 6
// baseline (231.303 us; speedup 1.0000x reference)
//
#include <hip/hip_runtime.h>

#define DDIM 128

typedef __bf16 bf16x8 __attribute__((ext_vector_type(8)));
typedef float  floatx4 __attribute__((ext_vector_type(4)));

// ---------------------------------------------------------------------------
// Kernel 1: one N-half of [U|V] = z @ W_combined per block (bf16 MFMA 16x16x32),
// output quantized to BIASED uint8 (code = q+128) with a per-node fp32 scale.
//   half=0: U[n][:] = row n of z@W1[:128] + b1   -> U8 + u_scale
//   half=1: V[n][:] = row n of z@W1[128:]        -> V8 + v_scale
// W-half staged once per block in LDS B-fragment order (32 KiB).
// ROUND-6: 2-DEEP register prefetch with statically-named buffers ra/rb
// (hand-unrolled x2 loop; no runtime-indexed arrays -> no scratch).
// Rationale: 1-deep version sat at VGPR=68 < ~112 needed to keep the
// prefetch live through MFMA -> compiler sank the loads to their use,
// collapsing the prefetch; kernel stayed latency-bound (22% HBM, 5% MFMA).
// 2-deep + named buffers forces ~16 KB/wave in flight (peak regs ~124,
// within launch_bounds(256,4)'s 128 cap). Watch: VGPR ~112-128 and k1
// WRITE_SIZE ~25.8 MB (if it balloons -> spilled -> revert).
// Epilogue: direct coalesced uint2 stores (permuted col layout: feature
// j*16+p lives at byte p*8+j; edge kernel un-permutes via W2[j*16+p]).
// ---------------------------------------------------------------------------
__global__ __launch_bounds__(256, 4) void precompute_uv_mfma_q8(
    const float* __restrict__ z, const float* __restrict__ W1,
    const float* __restrict__ b1,
    unsigned char* __restrict__ U8, unsigned char* __restrict__ V8,
    float* __restrict__ u_scale, float* __restrict__ v_scale,
    int N, int nchunks)
{
    __shared__ unsigned short WsF[32 * 64 * 8];                      // 32 KiB

    const int t    = threadIdx.x;
    const int lane = t & 63;
    const int w    = t >> 6;            // wave 0..3
    const int half = blockIdx.x;        // 0 -> U, 1 -> V
    unsigned char* __restrict__ dst8 = half ? V8 : U8;
    float*         __restrict__ dscl = half ? v_scale : u_scale;
    const float*   __restrict__ Wh   = W1 + (size_t)half * DDIM * DDIM;

    const int mrow = lane & 15;    // C/D col within 16-tile (feature sub-index)
    const int quad = lane >> 4;    // C/D row group
    const int gy   = gridDim.y;

    // ---- two statically-named raw A-tile buffers (2-deep prefetch) ----
    float4 ra[8], rb[8];

    auto issue_into = [&](float4 (&buf)[8], int ch) {
        int grow = ch * 64 + w * 16 + mrow;
        if (grow > N - 1) grow = N - 1;
        const float* zrow = z + (size_t)grow * DDIM;
        #pragma unroll
        for (int ks = 0; ks < 4; ++ks) {
            const int k0 = ks * 32 + quad * 8;
            buf[2 * ks]     = *(const float4*)(zrow + k0);
            buf[2 * ks + 1] = *(const float4*)(zrow + k0 + 4);
        }
    };

    auto cvt_frags = [&](const float4 (&buf)[8], bf16x8 (&afrag)[4]) {
        #pragma unroll
        for (int ks = 0; ks < 4; ++ks) {
            const float4 x0 = buf[2 * ks];
            const float4 x1 = buf[2 * ks + 1];
            unsigned pk[4];
            asm("v_cvt_pk_bf16_f32 %0, %1, %2" : "=v"(pk[0]) : "v"(x0.x), "v"(x0.y));
            asm("v_cvt_pk_bf16_f32 %0, %1, %2" : "=v"(pk[1]) : "v"(x0.z), "v"(x0.w));
            asm("v_cvt_pk_bf16_f32 %0, %1, %2" : "=v"(pk[2]) : "v"(x1.x), "v"(x1.y));
            asm("v_cvt_pk_bf16_f32 %0, %1, %2" : "=v"(pk[3]) : "v"(x1.z), "v"(x1.w));
            afrag[ks] = __builtin_bit_cast(bf16x8, *(const uint4*)pk);
        }
    };

    // bias per nt (col = nt*16 + mrow); b1 only applies to the U half.
    float bval[8];
    #pragma unroll
    for (int nt = 0; nt < 8; ++nt)
        bval[nt] = (half == 0) ? b1[nt * 16 + mrow] : 0.f;

    auto do_chunk = [&](const bf16x8 (&afrag)[4], int chunk) {
        floatx4 acc[8];
        #pragma unroll
        for (int nt = 0; nt < 8; ++nt)
            acc[nt] = (floatx4){bval[nt], bval[nt], bval[nt], bval[nt]};

        #pragma unroll
        for (int ks = 0; ks < 4; ++ks) {
            #pragma unroll
            for (int nt = 0; nt < 8; ++nt) {
                const bf16x8 b = __builtin_bit_cast(bf16x8,
                    *(const uint4*)&WsF[((nt * 4 + ks) * 64 + lane) * 8]);
                acc[nt] = __builtin_amdgcn_mfma_f32_16x16x32_bf16(afrag[ks], b, acc[nt], 0, 0, 0);
            }
        }

        // ---- quantize epilogue (no LDS, direct coalesced stores) ----
        // C-layout: value (nt,r) -> node row quad*4+r (local), col nt*16+mrow.
        #pragma unroll
        for (int r = 0; r < 4; ++r) {
            // triples -> v_max3_f32 with free abs input modifiers
            float mx = fmaxf(fmaxf(fabsf(acc[0][r]), fabsf(acc[1][r])),
                             fabsf(acc[2][r]));
            mx = fmaxf(fmaxf(mx, fabsf(acc[3][r])), fabsf(acc[4][r]));
            mx = fmaxf(fmaxf(mx, fabsf(acc[5][r])), fabsf(acc[6][r]));
            mx = fmaxf(mx, fabsf(acc[7][r]));
            // node row lives across the 16 lanes of this quad-group
            #pragma unroll
            for (int m = 1; m < 16; m <<= 1)
                mx = fmaxf(mx, __shfl_xor(mx, m, 16));
            mx = fmaxf(mx, 1e-20f);
            const float inv = 127.f * __builtin_amdgcn_rcpf(mx);

            // magic = 2^23 + 2^22 + 128 : RNE to integer, low byte = q+128
            unsigned char bytes[8];
            #pragma unroll
            for (int nt = 0; nt < 8; ++nt) {
                const float fq = fmaf(acc[nt][r], inv, 12583040.0f);
                bytes[nt] = (unsigned char)(__builtin_bit_cast(unsigned, fq) & 0xffu);
            }
            const int grow = chunk * 64 + w * 16 + quad * 4 + r;
            if (grow < N) {
                // quad-group covers bytes mrow*8..+7 of the row -> one dense
                // 128 B segment per quad, 4 segments per store instruction.
                *(uint2*)&dst8[(size_t)grow * DDIM + mrow * 8] =
                    *(const uint2*)bytes;
                if (mrow == 0) dscl[grow] = mx * (1.f / 127.f);
            }
        }
    };

    // ---- prologue: issue chunks c0 (-> ra) and c0+gy (-> rb) now; their
    // latency hides under W-staging below ----
    if (blockIdx.y < nchunks)      issue_into(ra, blockIdx.y);
    if (blockIdx.y + gy < nchunks) issue_into(rb, blockIdx.y + gy);

    // ---- stage W-half fragments (once per block), packed bf16 via cvt_pk ----
    {
        const int nlow = lane & 15;
        const int kq   = (lane >> 4) & 3;
        #pragma unroll
        for (int i = 0; i < 8; ++i) {
            const int ntks = w + i * 4;              // 0..31
            const int nt = ntks >> 2, ks = ntks & 3;
            const int n  = nt * 16 + nlow;
            const int kb = ks * 32 + kq * 8;
            float f[8];
            #pragma unroll
            for (int j = 0; j < 8; ++j)
                f[j] = Wh[(kb + j) * DDIM + n];
            unsigned pk[4];
            #pragma unroll
            for (int j = 0; j < 4; ++j)
                asm("v_cvt_pk_bf16_f32 %0, %1, %2"
                    : "=v"(pk[j]) : "v"(f[2 * j]), "v"(f[2 * j + 1]));
            *(uint4*)&WsF[(ntks * 64 + lane) * 8] = *(const uint4*)pk;
        }
    }

    __syncthreads();

    // ---- hand-unrolled x2 main loop: A-buffer iteration, B-buffer iteration.
    // At chunk c (buffer X), reload X with chunk c+2*gy. ----
    int chunk = blockIdx.y;
    while (chunk < nchunks) {
        {   // --- ra iteration ---
            bf16x8 afrag[4];
            cvt_frags(ra, afrag);                 // waits on ra's loads only
            const int n2 = chunk + 2 * gy;
            if (n2 < nchunks) issue_into(ra, n2); // back in flight immediately
            do_chunk(afrag, chunk);
        }
        chunk += gy;
        if (chunk >= nchunks) break;
        {   // --- rb iteration ---
            bf16x8 afrag[4];
            cvt_frags(rb, afrag);
            const int n2 = chunk + 2 * gy;
            if (n2 < nchunks) issue_into(rb, n2);
            do_chunk(afrag, chunk);
        }
        chunk += gy;
    }
}

// ---------------------------------------------------------------------------
// Kernel 2: per-edge gather (biased-uint8 U/V + per-node scales) + relu + dot(W2).
// 16 lanes per group, 4 edges per group. Lane p's 8 bytes are permuted cols
// j*16+p, so ww[j] = W2[j*16+p].
// Dequant: h_j = su*(u8-128) + sv*(v8-128) = su*u8f + sv*v8f + c,
//          c = -128*(su+sv) once per edge. (x>>8j)&0xff + uitofp matches the
// hardware v_cvt_f32_ubyte{0..3} pattern -> 1 op per byte.
// ---------------------------------------------------------------------------
__global__ __launch_bounds__(256) void edge_kernel_i8(
    const int* __restrict__ ei,
    const unsigned char* __restrict__ U8, const unsigned char* __restrict__ V8,
    const float* __restrict__ u_scale, const float* __restrict__ v_scale,
    const float* __restrict__ W2, const float* __restrict__ b2,
    float* __restrict__ out, int E)
{
    const int t  = threadIdx.x;
    const int p  = t & 15;
    const int g0 = (blockIdx.x * 16 + (t >> 4)) * 4;   // first of 4 edges
    if (g0 >= E) return;

    float ww[8];
    #pragma unroll
    for (int j = 0; j < 8; ++j) ww[j] = W2[j * 16 + p];

    int rows[4], cols[4];
    if (g0 + 3 < E) {
        const int4 r4 = *(const int4*)(ei + g0);
        const int4 c4 = *(const int4*)(ei + (size_t)E + g0);
        rows[0]=r4.x; rows[1]=r4.y; rows[2]=r4.z; rows[3]=r4.w;
        cols[0]=c4.x; cols[1]=c4.y; cols[2]=c4.z; cols[3]=c4.w;
    } else {
        #pragma unroll
        for (int i = 0; i < 4; ++i) {
            const int gi = (g0 + i < E) ? (g0 + i) : (E - 1);
            rows[i] = ei[gi];
            cols[i] = ei[(size_t)E + gi];
        }
    }

    uint2 uu[4], vv[4];
    #pragma unroll
    for (int i = 0; i < 4; ++i)
        uu[i] = *(const uint2*)(U8 + (size_t)rows[i] * DDIM + p * 8);
    #pragma unroll
    for (int i = 0; i < 4; ++i)
        vv[i] = *(const uint2*)(V8 + (size_t)cols[i] * DDIM + p * 8);

    float su[4], sv[4];
    #pragma unroll
    for (int i = 0; i < 4; ++i) { su[i] = u_scale[rows[i]]; sv[i] = v_scale[cols[i]]; }

    const float bias = b2[0];

    float sres[4];
    #pragma unroll
    for (int i = 0; i < 4; ++i) {
        const unsigned ul = uu[i].x, uh = uu[i].y;
        const unsigned vl = vv[i].x, vh = vv[i].y;
        const float c = -128.f * (su[i] + sv[i]);
        float s = 0.f;
        #pragma unroll
        for (int j = 0; j < 4; ++j) {
            const float uf = (float)((ul >> (8 * j)) & 0xffu);
            const float vf = (float)((vl >> (8 * j)) & 0xffu);
            const float h  = fmaf(su[i], uf, fmaf(sv[i], vf, c));
            s = fmaf(fmaxf(h, 0.f), ww[j], s);
        }
        #pragma unroll
        for (int j = 0; j < 4; ++j) {
            const float uf = (float)((uh >> (8 * j)) & 0xffu);
            const float vf = (float)((vh >> (8 * j)) & 0xffu);
            const float h  = fmaf(su[i], uf, fmaf(sv[i], vf, c));
            s = fmaf(fmaxf(h, 0.f), ww[4 + j], s);
        }
        #pragma unroll
        for (int off = 8; off > 0; off >>= 1)
            s += __shfl_down(s, off, 16);
        sres[i] = s + bias;
    }

    // packed result store: one float4 per 16-lane group
    if (p == 0) {
        if (g0 + 3 < E) {
            float4 o; o.x = sres[0]; o.y = sres[1]; o.z = sres[2]; o.w = sres[3];
            *(float4*)&out[g0] = o;
        } else {
            #pragma unroll
            for (int i = 0; i < 4; ++i)
                if (g0 + i < E) out[g0 + i] = sres[i];
        }
    }
}

// ---------------------------------------------------------------------------
// Fallback (ws too small): fused per-edge fp32 GEMV (known-correct path).
// ---------------------------------------------------------------------------
__global__ __launch_bounds__(256) void edge_fused_fallback(
    const float* __restrict__ z, const int* __restrict__ ei,
    const float* __restrict__ W1, const float* __restrict__ b1,
    const float* __restrict__ W2, const float* __restrict__ b2,
    float* __restrict__ out, int N, int E)
{
    const int tid  = blockIdx.x * 256 + threadIdx.x;
    const int e    = tid >> 6;
    const int lane = tid & 63;
    if (e >= E) return;

    const int row = ei[e];
    const int col = ei[(size_t)E + e];
    const float* zr = z + (size_t)row * DDIM;
    const float* zc = z + (size_t)col * DDIM;

    float h0 = b1[lane];
    float h1 = b1[lane + 64];
    for (int k = 0; k < DDIM; ++k) {
        const float a = zr[k];
        const float b = zc[k];
        h0 = fmaf(a, W1[k * DDIM + lane],               h0);
        h0 = fmaf(b, W1[(DDIM + k) * DDIM + lane],      h0);
        h1 = fmaf(a, W1[k * DDIM + lane + 64],          h1);
        h1 = fmaf(b, W1[(DDIM + k) * DDIM + lane + 64], h1);
    }
    float s = fmaxf(h0, 0.f) * W2[lane] + fmaxf(h1, 0.f) * W2[lane + 64];
    #pragma unroll
    for (int off = 32; off > 0; off >>= 1)
        s += __shfl_down(s, off, 64);
    if (lane == 0) out[e] = s + b2[0];
}

extern "C" void kernel_launch(void* const* d_in, const int* in_sizes, int n_in,
                              void* d_out, int out_size, void* d_ws, size_t ws_size,
                              hipStream_t stream)
{
    const float* z  = (const float*)d_in[0];
    const int*   ei = (const int*)d_in[1];       // int32 per harness convention
    const float* W1 = (const float*)d_in[2];
    const float* b1 = (const float*)d_in[3];
    const float* W2 = (const float*)d_in[4];
    const float* b2 = (const float*)d_in[5];
    float*       out = (float*)d_out;

    const int N = in_sizes[0] / DDIM;
    const int E = in_sizes[1] / 2;

    const size_t n128 = (size_t)N * DDIM;
    const size_t need = 2 * n128 + 2 * (size_t)N * sizeof(float) + 256;
    if (ws_size >= need) {
        unsigned char* U8 = (unsigned char*)d_ws;
        unsigned char* V8 = U8 + n128;
        float* usc = (float*)(((size_t)(V8 + n128) + 255) & ~(size_t)255);
        float* vsc = usc + N;
        const int nchunks = (N + 63) / 64;
        // 2 x 512 = 1024 blocks (single dispatch generation, 4 blocks/CU),
        // CPB ~3 grid-stride with 2-deep named-buffer register prefetch.
        const int gy = nchunks < 512 ? nchunks : 512;
        hipLaunchKernelGGL(precompute_uv_mfma_q8, dim3(2, gy), dim3(256), 0, stream,
                           z, W1, b1, U8, V8, usc, vsc, N, nchunks);
        hipLaunchKernelGGL(edge_kernel_i8, dim3((E + 63) / 64), dim3(256), 0, stream,
                           ei, U8, V8, usc, vsc, W2, b2, out, E);
    } else {
        hipLaunchKernelGGL(edge_fused_fallback, dim3((E + 3) / 4), dim3(256), 0, stream,
                           z, ei, W1, b1, W2, b2, out, N, E);
    }
}

// Round 7
// 138.650 us; speedup vs baseline: 1.6683x; 1.6683x over previous
//
#include <hip/hip_runtime.h>

#define DDIM 128

typedef __bf16 bf16x8 __attribute__((ext_vector_type(8)));
typedef float  floatx4 __attribute__((ext_vector_type(4)));

// ---------------------------------------------------------------------------
// Kernel 1: one N-half of [U|V] = z @ W_combined per block (bf16 MFMA 16x16x32),
// output quantized to BIASED uint8 (code = q+128) with a per-node fp32 scale.
//   half=0: U[n][:] = row n of z@W1[:128] + b1   -> U8 + u_scale
//   half=1: V[n][:] = row n of z@W1[128:]        -> V8 + v_scale
// W-half staged once per block in LDS B-fragment order (32 KiB).
// FROZEN at the round-5 structure (best measured): 256 thr, 1-deep register
// prefetch, VGPR~68, no spill, grid (2,512) single dispatch generation.
// Post-mortems: 512-thr (r4) and 2-deep named-buffer prefetch (r6) BOTH
// spilled (WRITE_SIZE 25.8 -> 57/284 MB scratch) — hipcc's occupancy
// heuristic refuses >64ish arch-VGPRs of live prefetch state here. Do not
// re-attempt deeper register prefetch on this shape.
// Epilogue: direct coalesced uint2 stores (permuted col layout: feature
// j*16+p lives at byte p*8+j within each 128-B row).
// ---------------------------------------------------------------------------
__global__ __launch_bounds__(256, 4) void precompute_uv_mfma_q8(
    const float* __restrict__ z, const float* __restrict__ W1,
    const float* __restrict__ b1,
    unsigned char* __restrict__ U8, unsigned char* __restrict__ V8,
    float* __restrict__ u_scale, float* __restrict__ v_scale,
    int N, int nchunks)
{
    __shared__ unsigned short WsF[32 * 64 * 8];                      // 32 KiB

    const int t    = threadIdx.x;
    const int lane = t & 63;
    const int w    = t >> 6;            // wave 0..3
    const int half = blockIdx.x;        // 0 -> U, 1 -> V
    unsigned char* __restrict__ dst8 = half ? V8 : U8;
    float*         __restrict__ dscl = half ? v_scale : u_scale;
    const float*   __restrict__ Wh   = W1 + (size_t)half * DDIM * DDIM;

    const int mrow = lane & 15;    // C/D col within 16-tile (feature sub-index)
    const int quad = lane >> 4;    // C/D row group
    const int gy   = gridDim.y;

    // ---- raw A-tile register buffer (1-deep prefetch) ----
    float4 rx[8];
    auto issue_loads = [&](int ch) {
        int grow = ch * 64 + w * 16 + mrow;
        if (grow > N - 1) grow = N - 1;
        const float* zrow = z + (size_t)grow * DDIM;
        #pragma unroll
        for (int ks = 0; ks < 4; ++ks) {
            const int k0 = ks * 32 + quad * 8;
            rx[2 * ks]     = *(const float4*)(zrow + k0);
            rx[2 * ks + 1] = *(const float4*)(zrow + k0 + 4);
        }
    };

    // issue first chunk's loads NOW; latency hides under W-staging below
    if (blockIdx.y < nchunks) issue_loads(blockIdx.y);

    // ---- stage W-half fragments (once per block), packed bf16 via cvt_pk ----
    {
        const int nlow = lane & 15;
        const int kq   = (lane >> 4) & 3;
        #pragma unroll
        for (int i = 0; i < 8; ++i) {
            const int ntks = w + i * 4;              // 0..31
            const int nt = ntks >> 2, ks = ntks & 3;
            const int n  = nt * 16 + nlow;
            const int kb = ks * 32 + kq * 8;
            float f[8];
            #pragma unroll
            for (int j = 0; j < 8; ++j)
                f[j] = Wh[(kb + j) * DDIM + n];
            unsigned pk[4];
            #pragma unroll
            for (int j = 0; j < 4; ++j)
                asm("v_cvt_pk_bf16_f32 %0, %1, %2"
                    : "=v"(pk[j]) : "v"(f[2 * j]), "v"(f[2 * j + 1]));
            *(uint4*)&WsF[(ntks * 64 + lane) * 8] = *(const uint4*)pk;
        }
    }

    // bias per nt (col = nt*16 + mrow); b1 only applies to the U half.
    float bval[8];
    #pragma unroll
    for (int nt = 0; nt < 8; ++nt)
        bval[nt] = (half == 0) ? b1[nt * 16 + mrow] : 0.f;

    __syncthreads();

    for (int chunk = blockIdx.y; chunk < nchunks; chunk += gy) {
        // ---- convert raw regs to A fragments ----
        bf16x8 afrag[4];
        #pragma unroll
        for (int ks = 0; ks < 4; ++ks) {
            const float4 x0 = rx[2 * ks];
            const float4 x1 = rx[2 * ks + 1];
            unsigned pk[4];
            asm("v_cvt_pk_bf16_f32 %0, %1, %2" : "=v"(pk[0]) : "v"(x0.x), "v"(x0.y));
            asm("v_cvt_pk_bf16_f32 %0, %1, %2" : "=v"(pk[1]) : "v"(x0.z), "v"(x0.w));
            asm("v_cvt_pk_bf16_f32 %0, %1, %2" : "=v"(pk[2]) : "v"(x1.x), "v"(x1.y));
            asm("v_cvt_pk_bf16_f32 %0, %1, %2" : "=v"(pk[3]) : "v"(x1.z), "v"(x1.w));
            afrag[ks] = __builtin_bit_cast(bf16x8, *(const uint4*)pk);
        }

        // ---- prefetch next chunk's raw A-tile ----
        const int nxt = chunk + gy;
        if (nxt < nchunks) issue_loads(nxt);

        floatx4 acc[8];
        #pragma unroll
        for (int nt = 0; nt < 8; ++nt)
            acc[nt] = (floatx4){bval[nt], bval[nt], bval[nt], bval[nt]};

        #pragma unroll
        for (int ks = 0; ks < 4; ++ks) {
            #pragma unroll
            for (int nt = 0; nt < 8; ++nt) {
                const bf16x8 b = __builtin_bit_cast(bf16x8,
                    *(const uint4*)&WsF[((nt * 4 + ks) * 64 + lane) * 8]);
                acc[nt] = __builtin_amdgcn_mfma_f32_16x16x32_bf16(afrag[ks], b, acc[nt], 0, 0, 0);
            }
        }

        // ---- quantize epilogue (no LDS, direct coalesced stores) ----
        // C-layout: value (nt,r) -> node row quad*4+r (local), col nt*16+mrow.
        #pragma unroll
        for (int r = 0; r < 4; ++r) {
            // triples -> v_max3_f32 with free abs input modifiers
            float mx = fmaxf(fmaxf(fabsf(acc[0][r]), fabsf(acc[1][r])),
                             fabsf(acc[2][r]));
            mx = fmaxf(fmaxf(mx, fabsf(acc[3][r])), fabsf(acc[4][r]));
            mx = fmaxf(fmaxf(mx, fabsf(acc[5][r])), fabsf(acc[6][r]));
            mx = fmaxf(mx, fabsf(acc[7][r]));
            // node row lives across the 16 lanes of this quad-group
            #pragma unroll
            for (int m = 1; m < 16; m <<= 1)
                mx = fmaxf(mx, __shfl_xor(mx, m, 16));
            mx = fmaxf(mx, 1e-20f);
            const float inv = 127.f * __builtin_amdgcn_rcpf(mx);

            // magic = 2^23 + 2^22 + 128 : RNE to integer, low byte = q+128
            unsigned char bytes[8];
            #pragma unroll
            for (int nt = 0; nt < 8; ++nt) {
                const float fq = fmaf(acc[nt][r], inv, 12583040.0f);
                bytes[nt] = (unsigned char)(__builtin_bit_cast(unsigned, fq) & 0xffu);
            }
            const int grow = chunk * 64 + w * 16 + quad * 4 + r;
            if (grow < N) {
                *(uint2*)&dst8[(size_t)grow * DDIM + mrow * 8] =
                    *(const uint2*)bytes;
                if (mrow == 0) dscl[grow] = mx * (1.f / 127.f);
            }
        }
    }
}

// ---------------------------------------------------------------------------
// Kernel 2 (this round's change): per-edge gather + relu + dot(W2), now with
// 8 lanes per edge and 16-B uint4 gathers (was 16 lanes / 8-B uint2).
//   - halves the gather instruction count (same bytes, 1 KB per instruction,
//     8 rows per instruction), halves scale-load instruction count per edge
//   - reduction is 3 shfl instead of 4
// Permuted byte layout: row byte b holds feature (b&7)*16 + (b>>3).
// Lane q reads bytes 16q..16q+15, so byte k of the load is feature
//   (k&7)*16 + 2q + (k>>3)   ->  ww[k] = W2[(k&7)*16 + 2*q + (k>>3)].
// Dequant: h = su*u8f + sv*v8f + c, c = -128*(su+sv) once per edge;
// (x>>8j)&0xff + uitofp matches v_cvt_f32_ubyte{0..3} -> 1 op per byte.
// ---------------------------------------------------------------------------
__global__ __launch_bounds__(256) void edge_kernel_i8(
    const int* __restrict__ ei,
    const unsigned char* __restrict__ U8, const unsigned char* __restrict__ V8,
    const float* __restrict__ u_scale, const float* __restrict__ v_scale,
    const float* __restrict__ W2, const float* __restrict__ b2,
    float* __restrict__ out, int E)
{
    const int t  = threadIdx.x;
    const int q  = t & 7;                              // lane within 8-lane group
    const int g0 = (blockIdx.x * 32 + (t >> 3)) * 4;   // first of this group's 4 edges
    if (g0 >= E) return;

    float ww[16];
    #pragma unroll
    for (int k = 0; k < 16; ++k)
        ww[k] = W2[(k & 7) * 16 + 2 * q + (k >> 3)];

    int rows[4], cols[4];
    if (g0 + 3 < E) {
        const int4 r4 = *(const int4*)(ei + g0);
        const int4 c4 = *(const int4*)(ei + (size_t)E + g0);
        rows[0]=r4.x; rows[1]=r4.y; rows[2]=r4.z; rows[3]=r4.w;
        cols[0]=c4.x; cols[1]=c4.y; cols[2]=c4.z; cols[3]=c4.w;
    } else {
        #pragma unroll
        for (int i = 0; i < 4; ++i) {
            const int gi = (g0 + i < E) ? (g0 + i) : (E - 1);
            rows[i] = ei[gi];
            cols[i] = ei[(size_t)E + gi];
        }
    }

    uint4 uu[4], vv[4];
    #pragma unroll
    for (int i = 0; i < 4; ++i)
        uu[i] = *(const uint4*)(U8 + (size_t)rows[i] * DDIM + q * 16);
    #pragma unroll
    for (int i = 0; i < 4; ++i)
        vv[i] = *(const uint4*)(V8 + (size_t)cols[i] * DDIM + q * 16);

    float su[4], sv[4];
    #pragma unroll
    for (int i = 0; i < 4; ++i) { su[i] = u_scale[rows[i]]; sv[i] = v_scale[cols[i]]; }

    const float bias = b2[0];

    float sres[4];
    #pragma unroll
    for (int i = 0; i < 4; ++i) {
        const unsigned uw0 = uu[i].x, uw1 = uu[i].y, uw2 = uu[i].z, uw3 = uu[i].w;
        const unsigned vw0 = vv[i].x, vw1 = vv[i].y, vw2 = vv[i].z, vw3 = vv[i].w;
        const float c = -128.f * (su[i] + sv[i]);
        float s = 0.f;
        #pragma unroll
        for (int k = 0; k < 16; ++k) {
            const unsigned uwk = (k < 4) ? uw0 : (k < 8) ? uw1 : (k < 12) ? uw2 : uw3;
            const unsigned vwk = (k < 4) ? vw0 : (k < 8) ? vw1 : (k < 12) ? vw2 : vw3;
            const float uf = (float)((uwk >> (8 * (k & 3))) & 0xffu);
            const float vf = (float)((vwk >> (8 * (k & 3))) & 0xffu);
            const float h  = fmaf(su[i], uf, fmaf(sv[i], vf, c));
            s = fmaf(fmaxf(h, 0.f), ww[k], s);
        }
        s += __shfl_down(s, 4, 8);
        s += __shfl_down(s, 2, 8);
        s += __shfl_down(s, 1, 8);
        sres[i] = s + bias;
    }

    // packed result store: one float4 per 8-lane group
    if (q == 0) {
        if (g0 + 3 < E) {
            float4 o; o.x = sres[0]; o.y = sres[1]; o.z = sres[2]; o.w = sres[3];
            *(float4*)&out[g0] = o;
        } else {
            #pragma unroll
            for (int i = 0; i < 4; ++i)
                if (g0 + i < E) out[g0 + i] = sres[i];
        }
    }
}

// ---------------------------------------------------------------------------
// Fallback (ws too small): fused per-edge fp32 GEMV (known-correct path).
// ---------------------------------------------------------------------------
__global__ __launch_bounds__(256) void edge_fused_fallback(
    const float* __restrict__ z, const int* __restrict__ ei,
    const float* __restrict__ W1, const float* __restrict__ b1,
    const float* __restrict__ W2, const float* __restrict__ b2,
    float* __restrict__ out, int N, int E)
{
    const int tid  = blockIdx.x * 256 + threadIdx.x;
    const int e    = tid >> 6;
    const int lane = tid & 63;
    if (e >= E) return;

    const int row = ei[e];
    const int col = ei[(size_t)E + e];
    const float* zr = z + (size_t)row * DDIM;
    const float* zc = z + (size_t)col * DDIM;

    float h0 = b1[lane];
    float h1 = b1[lane + 64];
    for (int k = 0; k < DDIM; ++k) {
        const float a = zr[k];
        const float b = zc[k];
        h0 = fmaf(a, W1[k * DDIM + lane],               h0);
        h0 = fmaf(b, W1[(DDIM + k) * DDIM + lane],      h0);
        h1 = fmaf(a, W1[k * DDIM + lane + 64],          h1);
        h1 = fmaf(b, W1[(DDIM + k) * DDIM + lane + 64], h1);
    }
    float s = fmaxf(h0, 0.f) * W2[lane] + fmaxf(h1, 0.f) * W2[lane + 64];
    #pragma unroll
    for (int off = 32; off > 0; off >>= 1)
        s += __shfl_down(s, off, 64);
    if (lane == 0) out[e] = s + b2[0];
}

extern "C" void kernel_launch(void* const* d_in, const int* in_sizes, int n_in,
                              void* d_out, int out_size, void* d_ws, size_t ws_size,
                              hipStream_t stream)
{
    const float* z  = (const float*)d_in[0];
    const int*   ei = (const int*)d_in[1];       // int32 per harness convention
    const float* W1 = (const float*)d_in[2];
    const float* b1 = (const float*)d_in[3];
    const float* W2 = (const float*)d_in[4];
    const float* b2 = (const float*)d_in[5];
    float*       out = (float*)d_out;

    const int N = in_sizes[0] / DDIM;
    const int E = in_sizes[1] / 2;

    const size_t n128 = (size_t)N * DDIM;
    const size_t need = 2 * n128 + 2 * (size_t)N * sizeof(float) + 256;
    if (ws_size >= need) {
        unsigned char* U8 = (unsigned char*)d_ws;
        unsigned char* V8 = U8 + n128;
        float* usc = (float*)(((size_t)(V8 + n128) + 255) & ~(size_t)255);
        float* vsc = usc + N;
        const int nchunks = (N + 63) / 64;
        // 2 x 512 = 1024 blocks (single dispatch generation, 4 blocks/CU),
        // CPB ~3 grid-stride with 1-deep register prefetch (round-5 proven).
        const int gy = nchunks < 512 ? nchunks : 512;
        hipLaunchKernelGGL(precompute_uv_mfma_q8, dim3(2, gy), dim3(256), 0, stream,
                           z, W1, b1, U8, V8, usc, vsc, N, nchunks);
        // edge kernel: 128 edges per 256-thread block (8 lanes/edge, 4/group)
        hipLaunchKernelGGL(edge_kernel_i8, dim3((E + 127) / 128), dim3(256), 0, stream,
                           ei, U8, V8, usc, vsc, W2, b2, out, E);
    } else {
        hipLaunchKernelGGL(edge_fused_fallback, dim3((E + 3) / 4), dim3(256), 0, stream,
                           z, ei, W1, b1, W2, b2, out, N, E);
    }
}